// Round 1
// baseline (2408.560 us; speedup 1.0000x reference)
//
#include <hip/hip_runtime.h>

#define TT 2048
#define BB 256
#define FF 64
#define HH 128
#define NTHREADS 384  // 128 r-cols + 128 z-cols + 128 n-cols

__global__ __launch_bounds__(NTHREADS, 1) void gru_scan_kernel(
    const float* __restrict__ x,     // [T,B,F]
    const float* __restrict__ Wi,    // [F,3H] packed r|z|n
    const float* __restrict__ bi,    // [3H]
    const float* __restrict__ Whrz,  // [H,2H] packed r|z
    const float* __restrict__ Whn,   // [H,H]
    const float* __restrict__ bn,    // [H]
    float* __restrict__ out)         // [T,B,H]
{
  const int b = blockIdx.x;   // batch row (independent recurrence)
  const int j = threadIdx.x;  // output column 0..383

  __shared__ __align__(16) float h_lds[HH];
  __shared__ __align__(16) float x_lds[2][FF];
  // pre[128:256) = z, pre[256:384) = hn (h@Whn + bn), pre[384:512) = xin (x@Win + bi_n)
  __shared__ __align__(16) float pre[4 * HH];

  // ---- weights stationary in registers (per-thread column) ----
  float wi[FF];
  float wh[HH];
  #pragma unroll
  for (int k = 0; k < FF; ++k) wi[k] = Wi[k * 384 + j];
  if (j < 256) {
    #pragma unroll
    for (int k = 0; k < HH; ++k) wh[k] = Whrz[k * 256 + j];
  } else {
    #pragma unroll
    for (int k = 0; k < HH; ++k) wh[k] = Whn[k * 128 + (j - 256)];
  }
  const float bias_i = bi[j];
  const float bias_n = (j >= 256) ? bn[j - 256] : 0.0f;

  // ---- init h = 0, stage x[t=0] ----
  if (j < HH) h_lds[j] = 0.0f;
  if (j < FF / 4) {
    *(float4*)&x_lds[0][j * 4] = *(const float4*)&x[(size_t)b * FF + j * 4];
  }
  __syncthreads();

  for (int t = 0; t < TT; ++t) {
    // prefetch next x row into registers (hidden under the dots)
    float4 xnext;
    const bool loader = (j < FF / 4) && (t + 1 < TT);
    if (loader) {
      xnext = *(const float4*)&x[((size_t)(t + 1) * BB + b) * FF + j * 4];
    }

    // input-projection dot (length 64), LDS broadcast reads
    const float4* xc4 = (const float4*)x_lds[t & 1];
    float a0 = 0.f, a1 = 0.f, a2 = 0.f, a3 = 0.f;
    #pragma unroll
    for (int kk = 0; kk < FF / 4; ++kk) {
      float4 v = xc4[kk];
      a0 += v.x * wi[4 * kk + 0];
      a1 += v.y * wi[4 * kk + 1];
      a2 += v.z * wi[4 * kk + 2];
      a3 += v.w * wi[4 * kk + 3];
    }
    const float acc_i = bias_i + ((a0 + a1) + (a2 + a3));

    // recurrent dot (length 128), LDS broadcast reads
    const float4* h4 = (const float4*)h_lds;
    float b0 = 0.f, b1 = 0.f, b2 = 0.f, b3 = 0.f;
    #pragma unroll
    for (int kk = 0; kk < HH / 4; ++kk) {
      float4 v = h4[kk];
      b0 += v.x * wh[4 * kk + 0];
      b1 += v.y * wh[4 * kk + 1];
      b2 += v.z * wh[4 * kk + 2];
      b3 += v.w * wh[4 * kk + 3];
    }
    const float acc_h = (b0 + b1) + (b2 + b3);

    float r = 0.0f;
    if (j < 128) {
      // r-gate: keep in register, needed by this same thread at combine
      r = 1.0f / (1.0f + __expf(-(acc_i + acc_h)));
    } else if (j < 256) {
      pre[j] = 1.0f / (1.0f + __expf(-(acc_i + acc_h)));       // z
    } else {
      pre[j] = acc_h + bias_n;                                  // hn
      pre[j + 128] = acc_i;                                     // xin
    }
    __syncthreads();

    if (j < 128) {
      const float z   = pre[128 + j];
      const float hn  = pre[256 + j];
      const float xin = pre[384 + j];
      const float narg = xin + r * hn;
      // tanh(x) = 1 - 2/(exp(2x)+1); saturates correctly at +-inf
      const float n = 1.0f - 2.0f / (__expf(2.0f * narg) + 1.0f);
      const float h_old = h_lds[j];
      const float hnew = (1.0f - z) * n + z * h_old;
      h_lds[j] = hnew;
      out[((size_t)t * BB + b) * HH + j] = hnew;
    }
    if (loader) {
      *(float4*)&x_lds[(t + 1) & 1][j * 4] = xnext;
    }
    __syncthreads();
  }
}

extern "C" void kernel_launch(void* const* d_in, const int* in_sizes, int n_in,
                              void* d_out, int out_size, void* d_ws, size_t ws_size,
                              hipStream_t stream) {
  const float* x    = (const float*)d_in[0];
  const float* Wi   = (const float*)d_in[1];
  const float* bi   = (const float*)d_in[2];
  const float* Whrz = (const float*)d_in[3];
  const float* Whn  = (const float*)d_in[4];
  const float* bn   = (const float*)d_in[5];
  float* out = (float*)d_out;

  gru_scan_kernel<<<dim3(BB), dim3(NTHREADS), 0, stream>>>(
      x, Wi, bi, Whrz, Whn, bn, out);
}

// Round 2
// 1907.830 us; speedup vs baseline: 1.2625x; 1.2625x over previous
//
#include <hip/hip_runtime.h>

#define TT 2048
#define BB 256
#define FF 64
#define HH 128
#define NT 768   // 12 waves: waves 0-3 -> r cols, 4-7 -> z cols, 8-11 -> n cols
                 // within a wave: lanes 0-31 = k-half 0, lanes 32-63 = k-half 1

__global__ __launch_bounds__(NT, 3) void gru_scan_kernel(
    const float* __restrict__ x,     // [T,B,F]
    const float* __restrict__ Wi,    // [F,3H] packed r|z|n
    const float* __restrict__ bi,    // [3H]
    const float* __restrict__ Whrz,  // [H,2H] packed r|z
    const float* __restrict__ Whn,   // [H,H]
    const float* __restrict__ bn,    // [H]
    float* __restrict__ out)         // [T,B,H]
{
  const int b    = blockIdx.x;
  const int tid  = threadIdx.x;
  const int w    = tid >> 6;       // wave 0..11
  const int lane = tid & 63;
  const int half = lane >> 5;      // k-half 0/1
  const int sub  = lane & 31;
  const int j    = w * 32 + sub;   // output column 0..383

  __shared__ __align__(16) float h_lds[HH];
  __shared__ __align__(16) float x_lds[2][FF];
  __shared__ __align__(16) float pre_z[HH];
  __shared__ __align__(16) float pre_hn[HH];
  __shared__ __align__(16) float pre_xin[HH];

  // ---- stationary weights: 32 + 64 floats per thread (fits in VGPRs) ----
  float wi[FF / 2];
  float wh[HH / 2];
  const int kx0 = half * (FF / 2);
  const int kh0 = half * (HH / 2);
  #pragma unroll
  for (int k = 0; k < FF / 2; ++k) wi[k] = Wi[(size_t)(kx0 + k) * 384 + j];
  if (j < 256) {
    #pragma unroll
    for (int k = 0; k < HH / 2; ++k) wh[k] = Whrz[(size_t)(kh0 + k) * 256 + j];
  } else {
    #pragma unroll
    for (int k = 0; k < HH / 2; ++k) wh[k] = Whn[(size_t)(kh0 + k) * 128 + (j - 256)];
  }
  // biases folded into half-0 accumulator init
  const float bias_i = (half == 0) ? bi[j] : 0.0f;
  const float bias_h = (half == 0 && j >= 256) ? bn[j - 256] : 0.0f;

  // ---- init h = 0, stage x[t=0] ----
  if (tid < HH) h_lds[tid] = 0.0f;
  if (tid < FF / 4) {
    ((float4*)x_lds[0])[tid] = ((const float4*)(x + (size_t)b * FF))[tid];
  }
  float h_old = 0.0f;   // owned by (j<128, half==0) threads
  float r_reg = 0.0f;

  const bool loader = (tid >= NT - 16);   // wave 11, lanes 48-63
  const int  lidx   = tid - (NT - 16);
  __syncthreads();

  for (int t = 0; t < TT; ++t) {
    // issue next-x prefetch early (consumed after barrier1)
    float4 xnext;
    if (loader && t + 1 < TT) {
      xnext = ((const float4*)(x + ((size_t)(t + 1) * BB + b) * FF))[lidx];
    }

    // ---- input dot: 32 MACs over k in [kx0, kx0+32) ----
    const float4* xc = (const float4*)&x_lds[t & 1][kx0];
    float ai0 = bias_i, ai1 = 0.f, ai2 = 0.f, ai3 = 0.f;
    #pragma unroll
    for (int kk = 0; kk < FF / 8; ++kk) {
      float4 v = xc[kk];
      ai0 += v.x * wi[4 * kk + 0];
      ai1 += v.y * wi[4 * kk + 1];
      ai2 += v.z * wi[4 * kk + 2];
      ai3 += v.w * wi[4 * kk + 3];
    }
    float acc_i = (ai0 + ai1) + (ai2 + ai3);

    // ---- recurrent dot: 64 MACs over k in [kh0, kh0+64) ----
    const float4* hc = (const float4*)&h_lds[kh0];
    float ah0 = bias_h, ah1 = 0.f, ah2 = 0.f, ah3 = 0.f;
    #pragma unroll
    for (int kk = 0; kk < HH / 8; ++kk) {
      float4 v = hc[kk];
      ah0 += v.x * wh[4 * kk + 0];
      ah1 += v.y * wh[4 * kk + 1];
      ah2 += v.z * wh[4 * kk + 2];
      ah3 += v.w * wh[4 * kk + 3];
    }
    float acc_h = (ah0 + ah1) + (ah2 + ah3);

    // ---- cross-half reduce + gates (wave-uniform branches) ----
    if (j < 256) {
      float s = acc_i + acc_h;
      s += __shfl_xor(s, 32);
      float g = 1.0f / (1.0f + __expf(-s));
      if (j < 128) {
        r_reg = g;                         // r stays in-register
      } else if (half == 0) {
        pre_z[j - 128] = g;                // z
      }
    } else {
      float ti = acc_i + __shfl_xor(acc_i, 32);
      float th = acc_h + __shfl_xor(acc_h, 32);
      if (half == 0) {
        pre_hn[j - 256]  = th;             // h@Whn + bn
        pre_xin[j - 256] = ti;             // x@Win + bi_n
      }
    }
    __syncthreads();

    // ---- combine: 128 threads (r-cols, half 0) ----
    if (j < 128 && half == 0) {
      const float z   = pre_z[j];
      const float hn  = pre_hn[j];
      const float xin = pre_xin[j];
      const float narg = xin + r_reg * hn;
      const float n = 1.0f - 2.0f / (__expf(2.0f * narg) + 1.0f);
      const float hnew = z * (h_old - n) + n;   // (1-z)*n + z*h
      h_old = hnew;
      h_lds[j] = hnew;
      out[((size_t)t * BB + b) * HH + j] = hnew;
    }
    if (loader && t + 1 < TT) {
      ((float4*)x_lds[(t + 1) & 1])[lidx] = xnext;
    }
    __syncthreads();
  }
}

extern "C" void kernel_launch(void* const* d_in, const int* in_sizes, int n_in,
                              void* d_out, int out_size, void* d_ws, size_t ws_size,
                              hipStream_t stream) {
  const float* x    = (const float*)d_in[0];
  const float* Wi   = (const float*)d_in[1];
  const float* bi   = (const float*)d_in[2];
  const float* Whrz = (const float*)d_in[3];
  const float* Whn  = (const float*)d_in[4];
  const float* bn   = (const float*)d_in[5];
  float* out = (float*)d_out;

  gru_scan_kernel<<<dim3(BB), dim3(NT), 0, stream>>>(
      x, Wi, bi, Whrz, Whn, bn, out);
}